// Round 8
// baseline (3503.198 us; speedup 1.0000x reference)
//
#include <hip/hip_runtime.h>
#include <hip/hip_bf16.h>
#include <stdint.h>

// ---------------------------------------------------------------------------
// VGG attention-erase pipeline, bf16 MFMA implicit-im2col convs.
// Activations channels-last, spatially padded: [b][30 rows][32 cols][C] bf16.
// Weights pre-transposed to [p=9][O][C] bf16.
// conv_mfma v7 (P==9 path):
//  - SINGLE barrier per phase: [issue stages(t+2)][counted vmcnt][s_barrier]
//    [compute t]. Safety: overwrite target slot (t+2)&3 was last read in
//    compute(t-2) < barrier(t-1) < issue(t). W lead = 2 phases (lead 3 would
//    race); A staged at p==1 (barrier(t0) separates it from chunk k-1 reads).
//  - vmcnt FIFO: steady p in {1,2,3} -> keep 10, else keep 4;
//    last chunk: p<=6 -> 4, p7 -> 2, p8 -> 0.
//  - finer LDS swizzle col ^= (row&3) ^ ((row>>2)&3) on BOTH stage-source and
//    read side: ds_read_b128 frag reads go 4-way -> 2-way (free) bank quads.
//  - act loads NT (aux=2); panel-per-XCD grid (panel = id & 7); coalesced
//    LDS-staged epilogue. P==1 keeps the two-barrier v6 schedule.
//  LDS 80KB/block = 2 blocks/CU; 128 VGPR + 112 acc = 2 waves/SIMD.
//  (Round-7 bench was an infra failure; this is the same source resubmitted.)
// ---------------------------------------------------------------------------

typedef __attribute__((ext_vector_type(8))) short short8;
typedef __attribute__((ext_vector_type(4))) float floatx4;

__device__ __forceinline__ unsigned short f2bf(float f) {
  union { float f; uint32_t u; } cv; cv.f = f;
  uint32_t u = cv.u;
  u += 0x7fffu + ((u >> 16) & 1u);   // round-to-nearest-even
  return (unsigned short)(u >> 16);
}

// ---------------- weight prep: w[O][C][3][3] f32 -> wt[9][O][C] bf16 --------
__global__ void wprep3(const float* __restrict__ w, unsigned short* __restrict__ wt,
                       int O, int C) {
  int i = blockIdx.x * 256 + threadIdx.x;
  int total = 9 * O * C;
  if (i >= total) return;
  int p = i / (O * C);
  int r = i - p * O * C;
  int o = r / C;
  int c = r - o * C;
  wt[i] = f2bf(w[(size_t)(o * C + c) * 9 + p]);
}

// -------------- weight prep 1x1: w[O][C] f32 -> wt[OP][C] bf16 (zero pad) ---
__global__ void wprep1(const float* __restrict__ w, unsigned short* __restrict__ wt,
                       int O, int OP, int C) {
  int i = blockIdx.x * 256 + threadIdx.x;
  if (i >= OP * C) return;
  int o = i / C, c = i - o * C;
  wt[i] = (o < O) ? f2bf(w[(size_t)o * C + c]) : (unsigned short)0;
}

// ------ avgpool 3x3/9 (count_include_pad) + transpose to ch-last padded -----
// x: [32][512][28][28] f32  ->  fp: [32][30][32][512] bf16 (borders zero)
__global__ void avgpool_k(const float* __restrict__ x, unsigned short* __restrict__ fp) {
  const int C = 512;
  int b = blockIdx.x, r = blockIdx.y, cg = blockIdx.z;  // r: padded row 0..29
  int t = threadIdx.x;
  __shared__ float xs[3 * 128 * 29];   // stride 29 to kill bank conflicts
  if (r == 0 || r == 29) {
    for (int i = t; i < 32 * 128; i += 256) {
      int c = i & 127, col = i >> 7;
      fp[((size_t)(b * 30 + r) * 32 + col) * C + cg * 128 + c] = 0;
    }
    return;
  }
  for (int i = t; i < 3 * 128 * 28; i += 256) {
    int dy = i / 3584;
    int rem = i - dy * 3584;
    int c = rem / 28, fx = rem - c * 28;
    int fy = r - 2 + dy;
    float v = (fy >= 0 && fy < 28)
                  ? x[((size_t)(b * 512 + cg * 128 + c) * 28 + fy) * 28 + fx]
                  : 0.f;
    xs[(dy * 128 + c) * 29 + fx] = v;
  }
  __syncthreads();
  for (int i = t; i < 32 * 128; i += 256) {
    int c = i & 127, col = i >> 7;
    float v = 0.f;
    if (col >= 1 && col <= 28) {
      int fx0 = col - 1;
#pragma unroll
      for (int dy = 0; dy < 3; ++dy)
#pragma unroll
        for (int dx = 0; dx < 3; ++dx) {
          int fx = fx0 - 1 + dx;
          if (fx >= 0 && fx < 28) v += xs[(dy * 128 + c) * 29 + fx];
        }
      v *= (1.f / 9.f);
    }
    fp[((size_t)(b * 30 + r) * 32 + col) * C + cg * 128 + c] = f2bf(v);
  }
}

// ---------- zero the padded borders of h1p/h2p (ws is poisoned per call) ----
__global__ void zero_borders(unsigned short* __restrict__ h1,
                             unsigned short* __restrict__ h2, int Mch) {
  int i = blockIdx.x * 256 + threadIdx.x;
  int vch = Mch >> 3;                      // uint4 = 8 bf16
  int perbuf = 32 * 176 * vch;
  if (i >= 2 * perbuf) return;
  unsigned short* h = (i < perbuf) ? h1 : h2;
  int j = (i < perbuf) ? i : i - perbuf;
  int cv = j % vch;
  int rr = j / vch;
  int bidx = rr / 176, e = rr - bidx * 176;
  int row, col;
  if (e < 32)      { row = 0;  col = e; }
  else if (e < 64) { row = 29; col = e - 32; }
  else {
    int q = e - 64;
    row = 1 + (q >> 2);
    int k = q & 3;
    col = (k == 0) ? 0 : 28 + k;           // cols 0,29,30,31
  }
  size_t addr = ((size_t)(bidx * 30 + row) * 32 + col) * Mch + cv * 8;
  *(uint4*)&h[addr] = (uint4){0u, 0u, 0u, 0u};
}

// ------------------------------- the conv GEMM ------------------------------
// fin: [B][30][32][C] bf16, wt: [P][M][C] bf16, bias: [OB] f32
// PADOUT=1: out bf16 [B][30][32][M] (interior only). PADOUT=0: out f32 [B][784][M].
// grid 1D: panel = id & (2^XBITS-1) (panel-per-XCD); s = id >> XBITS.
template <int P, int RELU, int PADOUT, int XBITS>
__global__ __launch_bounds__(256, 2)
void conv_mfma(const unsigned short* __restrict__ fin,
               const unsigned short* __restrict__ wt,
               const float* __restrict__ bias,
               void* __restrict__ outp, int C, int M, int OB) {
  const int tid = threadIdx.x;
  const int lane = tid & 63;
  const int wave = tid >> 6;
  const int hB = wave & 1;      // batch half
  const int wo = wave >> 1;     // outch half
  const int ln = lane & 15;
  const int kq = lane >> 4;

  const int id = blockIdx.x;
  const int xo = id & ((1 << XBITS) - 1);   // weight panel (== XCD residue)
  const int s  = id >> XBITS;               // spatial-batch tile 0..111
  const int yo = s % 7;
  const int bz = s / 7;

  const int o0 = xo * 128 + wo * 64;
  const int wO0 = xo * 128;                 // block weight-row base (128 wide)
  const int yo0 = yo * 4;                   // first output row of tile
  const int b0 = bz * 2;
  const int bb = b0 + hB;

  // one LDS pool: [A: 2 x 1536 units][W: 4 x 512 units]; epilogue reuses it.
  __shared__ unsigned short ldsAll[40960];        // 81920 B
  unsigned short* ldsA = ldsAll;                  // 24576 shorts (49152 B)
  unsigned short* ldsW = ldsAll + 24576;          // 16384 shorts (32768 B)

  // spatial decomposition for A-fragment reads (m = ln within each 16-tile)
  int baserc[7];
#pragma unroll
  for (int mi = 0; mi < 7; ++mi) {
    int n = mi * 16 + ln;
    int y = n / 28, x = n - y * 28;
    baserc[mi] = y * 32 + x;
  }
  // weight fragment LDS offset (shorts): row = wo*64 + ni*16 + ln;
  // unit col = kq ^ (row&3) ^ ((row>>2)&3) = kq ^ (ln&3) ^ ((ln>>2)&3)
  const int wbase = wo * 2048 + ln * 32 + ((kq ^ (ln & 3) ^ ((ln >> 2) & 3)) << 3);

  floatx4 acc[7][4];
#pragma unroll
  for (int mi = 0; mi < 7; ++mi)
#pragma unroll
    for (int ni = 0; ni < 4; ++ni)
      acc[mi][ni] = (floatx4){0.f, 0.f, 0.f, 0.f};

  const size_t fin_base0 = (size_t)(b0 * 30 + yo0) * 32 * C;
  const size_t fin_base1 = (size_t)((b0 + 1) * 30 + yo0) * 32 * C;

  // staging constants: XOR swizzle on 16B-unit col, f(row,col)=col^(row&3)^((row>>2)&3)
  // (involution; row = chunkbase + rA with chunkbase % 64 == 0 -> use rA bits)
  const int rA = tid >> 2;                  // row-within-256-unit chunk
  const int cgA = (tid & 3) ^ (rA & 3) ^ ((rA >> 2) & 3);   // swizzled source col

  auto stageA = [&](int ck, int buf) {
#pragma unroll
    for (int it = 0; it < 6; ++it) {
      int wb = (it >= 3) ? 1 : 0;
      int it3 = it - wb * 3;
      int rc = it3 * 64 + rA;
      size_t goff = (wb ? fin_base1 : fin_base0) + (size_t)rc * C + ck + cgA * 8;
      unsigned short* lp = &ldsA[(unsigned)(buf * 1536 + wb * 768 + it3 * 256 + wave * 64) << 3];
      // aux=2 (NT/SLC): act stream must not evict the L2-resident weight panel
      __builtin_amdgcn_global_load_lds((const uint32_t*)(fin + goff), (uint32_t*)lp,
                                       16, 0, 2);
    }
  };
  auto stageW = [&](int p, int ck, int q) {   // q: ring slot 0..3
#pragma unroll
    for (int it = 0; it < 2; ++it) {
      int row = it * 64 + rA;
      size_t goff = (size_t)(p * M + wO0 + row) * C + ck + cgA * 8;
      unsigned short* lp = &ldsW[(unsigned)(q * 512 + it * 256 + wave * 64) << 3];
      __builtin_amdgcn_global_load_lds((const uint32_t*)(wt + goff), (uint32_t*)lp,
                                       16, 0, 0);
    }
  };

  // prologue. P==9: lead-2 W ring -> slots 0,1. P==1: v6 scheme (slot 0).
  stageA(0, 0);
  stageW(0, 0, 0);
  if (P == 9) stageW(1, 0, 1);

  int cur = 0;    // act read buffer
  int rq0 = 0;    // W ring slot of this chunk's phase 0
  for (int ck = 0; ck < C; ck += 32) {
    const bool last = (ck + 32 >= C);
#pragma unroll
    for (int p = 0; p < P; ++p) {
      if (P == 9) {
        // ---- single-barrier phase: issue(t+2) -> counted wait -> barrier ----
        if (!(last && p >= 7))
          stageW(p < 7 ? p + 2 : p - 7, p < 7 ? ck : ck + 32, (rq0 + p + 2) & 3);
        if (p == 1 && !last) stageA(ck + 32, cur ^ 1);

        if (!last) {
          if (p >= 1 && p <= 3) asm volatile("s_waitcnt vmcnt(10)" ::: "memory");
          else                  asm volatile("s_waitcnt vmcnt(4)" ::: "memory");
        } else {
          if (p < 7)            asm volatile("s_waitcnt vmcnt(4)" ::: "memory");
          else if (p == 7)      asm volatile("s_waitcnt vmcnt(2)" ::: "memory");
          else                  asm volatile("s_waitcnt vmcnt(0)" ::: "memory");
        }
        __builtin_amdgcn_sched_barrier(0);
        __builtin_amdgcn_s_barrier();
        __builtin_amdgcn_sched_barrier(0);
        asm volatile("" ::: "memory");   // no LDS read hoists above this point
      } else {
        // ---- P==1: two-barrier v6 schedule (proven) ----
        const bool fin_phase = last && (p == P - 1);
        __builtin_amdgcn_s_barrier();
        __builtin_amdgcn_sched_barrier(0);
        if (!last) stageW(0, ck + 32, (rq0 + p + 1) & 3);
        if (p == 0 && !last) stageA(ck + 32, cur ^ 1);
        if (fin_phase) asm volatile("s_waitcnt vmcnt(0)" ::: "memory");
        else           asm volatile("s_waitcnt vmcnt(8)" ::: "memory");
        __builtin_amdgcn_sched_barrier(0);
        __builtin_amdgcn_s_barrier();
        __builtin_amdgcn_sched_barrier(0);
        asm volatile("" ::: "memory");
      }

      // ---- compute phase p from LDS ----
      const unsigned short* wrd = &ldsW[(unsigned)(((rq0 + p) & 3) << 12)];
      const unsigned short* ard = &ldsA[cur ? 12288 : 0];
      int dy, dx;
      if (P == 1) { dy = 1; dx = 1; } else { dy = p / 3; dx = p - dy * 3; }
      short8 wf[4];
#pragma unroll
      for (int ni = 0; ni < 4; ++ni)
        wf[ni] = *(const short8*)(const void*)&wrd[wbase + ni * 512];
      short8 af[7];
#pragma unroll
      for (int mi = 0; mi < 7; ++mi) {
        int rc = baserc[mi] + dy * 32 + dx;
        int u = hB * 768 + (rc << 2) + (kq ^ (rc & 3) ^ ((rc >> 2) & 3));
        af[mi] = *(const short8*)(const void*)&ard[(unsigned)u << 3];
      }
      __builtin_amdgcn_s_setprio(1);
#pragma unroll
      for (int mi = 0; mi < 7; ++mi)
#pragma unroll
        for (int ni = 0; ni < 4; ++ni)
          acc[mi][ni] = __builtin_amdgcn_mfma_f32_16x16x32_bf16(af[mi], wf[ni],
                                                                acc[mi][ni], 0, 0, 0);
      __builtin_amdgcn_s_setprio(0);
    }
    rq0 = (rq0 + P) & 3;
    cur ^= 1;
  }

  // ---- epilogue ----  D[row=spatial=(kq*4+j within 16-tile)][col=outch=ln]
  float bia[4];
#pragma unroll
  for (int ni = 0; ni < 4; ++ni) {
    int o = o0 + ni * 16 + ln;
    bia[ni] = (o < OB) ? bias[o] : 0.f;
  }

  if (PADOUT) {
    // coalesced path: stage wave tile (112 rows x 64 outch bf16) in LDS
    // (stride 72 shorts = 144B, 16B-aligned rows), then 14 x dwordx4/lane.
    __builtin_amdgcn_s_barrier();   // all waves done reading ldsA/ldsW
    unsigned short* ep = ldsAll + wave * 8064;   // 112*72 shorts per wave
#pragma unroll
    for (int mi = 0; mi < 7; ++mi)
#pragma unroll
      for (int j = 0; j < 4; ++j) {
        int n = mi * 16 + kq * 4 + j;
#pragma unroll
        for (int ni = 0; ni < 4; ++ni) {
          float v = acc[mi][ni][j] + bia[ni];
          if (RELU) v = fmaxf(v, 0.f);
          ep[n * 72 + ni * 16 + ln] = f2bf(v);
        }
      }
    // same-wave producer/consumer: lgkmcnt drain is enough (no cross-wave)
    asm volatile("s_waitcnt lgkmcnt(0)" ::: "memory");
    __builtin_amdgcn_sched_barrier(0);
    const int rsub = lane >> 3;          // row within 8-row group
    const int oseg = (lane & 7) * 8;     // 8 bf16 = 16B segment
#pragma unroll
    for (int it = 0; it < 14; ++it) {
      int n = it * 8 + rsub;
      int y = n / 28, x = n - y * 28;
      uint4 v = *(const uint4*)&ep[n * 72 + oseg];
      size_t addr = ((size_t)(bb * 30 + yo0 + y + 1) * 32 + (x + 1)) * M + o0 + oseg;
      *(uint4*)&((unsigned short*)outp)[addr] = v;
    }
  } else {
#pragma unroll
    for (int mi = 0; mi < 7; ++mi) {
#pragma unroll
      for (int j = 0; j < 4; ++j) {
        int n = mi * 16 + kq * 4 + j;
        int y = n / 28, x = n - y * 28;
#pragma unroll
        for (int ni = 0; ni < 4; ++ni) {
          int o = o0 + ni * 16 + ln;
          float v = acc[mi][ni][j] + bia[ni];
          if (RELU) v = fmaxf(v, 0.f);
          size_t addr = ((size_t)bb * 784 + (yo0 + y) * 28 + x) * M + o;
          ((float*)outp)[addr] = v;
        }
      }
    }
  }
}

// ------------- logits (+ optional attention/mask), one block per batch ------
// ob: [32][784][256] f32 (cols 200..255 are zero)
template <int DO_ATTEN>
__global__ void logits_atten(const float* __restrict__ ob, const int* __restrict__ label,
                             float* __restrict__ outp, float* __restrict__ mask) {
  int b = blockIdx.x, t = threadIdx.x;
  const float* base = ob + (size_t)b * 784 * 256;
  float s = 0.f;
#pragma unroll 16
  for (int n = 0; n < 784; ++n) s += base[(size_t)n * 256 + t];
  if (t < 200) outp[b * 200 + t] = 1.f / (1.f + expf(-s * (1.f / 784.f)));

  if (DO_ATTEN) {
    __shared__ float labf[256];
    __shared__ float red[16];
    labf[t] = (t < 200) ? (float)label[b * 200 + t] : 0.f;
    __syncthreads();
    // normalization is invariant to the /cnt scaling -> skip it
    float att[4];
    float mn = 1e30f, mx = -1e30f;
#pragma unroll
    for (int i = 0; i < 4; ++i) {
      int n = t + i * 256;
      float a = 0.f;
      if (n < 784) {
        const float* rowp = base + (size_t)n * 256;
#pragma unroll 8
        for (int c = 0; c < 200; ++c) a += labf[c] * rowp[c];
        mn = fminf(mn, a);
        mx = fmaxf(mx, a);
      }
      att[i] = a;
    }
    for (int off = 32; off; off >>= 1) {
      mn = fminf(mn, __shfl_down(mn, off, 64));
      mx = fmaxf(mx, __shfl_down(mx, off, 64));
    }
    if ((t & 63) == 0) { red[(t >> 6) * 2] = mn; red[(t >> 6) * 2 + 1] = mx; }
    __syncthreads();
    if (t == 0) {
      float a = red[0], c = red[1];
      for (int wv = 1; wv < 4; ++wv) {
        a = fminf(a, red[wv * 2]);
        c = fmaxf(c, red[wv * 2 + 1]);
      }
      red[0] = a; red[1] = c;
    }
    __syncthreads();
    float gmn = red[0];
    float inv = 1.f / (red[1] - gmn);
#pragma unroll
    for (int i = 0; i < 4; ++i) {
      int n = t + i * 256;
      if (n < 784)
        mask[b * 784 + n] = ((att[i] - gmn) * inv >= 0.6f) ? 0.f : 1.f;
    }
  }
}

// ------------------- erase: featp interior *= mask (in place) ---------------
__global__ void erase_k(unsigned short* __restrict__ fp, const float* __restrict__ mask) {
  int i = blockIdx.x * 256 + threadIdx.x;
  if (i >= 32 * 28 * 28 * 512) return;
  int c = i & 511;
  int r2 = i >> 9;
  int xcol = r2 % 28;
  int r3 = r2 / 28;
  int y = r3 % 28;
  int b = r3 / 28;
  if (mask[b * 784 + y * 28 + xcol] == 0.f)
    fp[((size_t)(b * 30 + y + 1) * 32 + (xcol + 1)) * 512 + c] = 0;
}

// ---------------------------------------------------------------------------
extern "C" void kernel_launch(void* const* d_in, const int* in_sizes, int n_in,
                              void* d_out, int out_size, void* d_ws, size_t ws_size,
                              hipStream_t stream) {
  const float* x   = (const float*)d_in[0];
  const int* label = (const int*)d_in[1];
  const float* w1  = (const float*)d_in[2];
  const float* b1  = (const float*)d_in[3];
  const float* w2  = (const float*)d_in[4];
  const float* b2  = (const float*)d_in[5];
  const float* w3  = (const float*)d_in[6];
  const float* b3  = (const float*)d_in[7];
  const float* we1 = (const float*)d_in[8];
  const float* be1 = (const float*)d_in[9];
  const float* we2 = (const float*)d_in[10];
  const float* be2 = (const float*)d_in[11];
  const float* we3 = (const float*)d_in[12];
  const float* be3 = (const float*)d_in[13];
  float* outv = (float*)d_out;

  char* wp = (char*)d_ws;
  unsigned short* featp = (unsigned short*)wp; wp += 31457280;   // [32][30][32][512] bf16
  unsigned short* h1p   = (unsigned short*)wp; wp += 62914560;   // [32][30][32][1024] bf16
  unsigned short* h2p   = (unsigned short*)wp; wp += 62914560;
  unsigned short* Wt1   = (unsigned short*)wp; wp += 9437184;    // [9][1024][512]
  unsigned short* Wt2   = (unsigned short*)wp; wp += 18874368;   // [9][1024][1024]
  unsigned short* Wt3   = (unsigned short*)wp; wp += 524288;     // [256][1024]
  float* outbuf         = (float*)wp;          wp += 25690112;   // [32][784][256] f32
  float* maskb          = (float*)wp;          wp += 100352;     // [32][784]

  // prep (every launch: ws is re-poisoned by the harness)
  zero_borders<<<5632, 256, 0, stream>>>(h1p, h2p, 1024);
  avgpool_k<<<dim3(32, 30, 4), 256, 0, stream>>>(x, featp);
  wprep3<<<(9 * 1024 * 512 + 255) / 256, 256, 0, stream>>>(w1, Wt1, 1024, 512);
  wprep3<<<(9 * 1024 * 1024 + 255) / 256, 256, 0, stream>>>(w2, Wt2, 1024, 1024);
  wprep1<<<(256 * 1024 + 255) / 256, 256, 0, stream>>>(w3, Wt3, 200, 256, 1024);

  // head 1 (1D grids, panel = id & (2^XBITS-1) -> panel-per-XCD)
  conv_mfma<9, 1, 1, 3><<<896, 256, 0, stream>>>(featp, Wt1, b1, h1p, 512, 1024, 1024);
  conv_mfma<9, 1, 1, 3><<<896, 256, 0, stream>>>(h1p, Wt2, b2, h2p, 1024, 1024, 1024);
  conv_mfma<1, 0, 0, 1><<<224, 256, 0, stream>>>(h2p, Wt3, b3, outbuf, 1024, 256, 200);
  logits_atten<1><<<32, 256, 0, stream>>>(outbuf, label, outv, maskb);

  // erase + head 2 (reuse Wt/h buffers; h borders are still zero)
  erase_k<<<(32 * 28 * 28 * 512 + 255) / 256, 256, 0, stream>>>(featp, maskb);
  wprep3<<<(9 * 1024 * 512 + 255) / 256, 256, 0, stream>>>(we1, Wt1, 1024, 512);
  wprep3<<<(9 * 1024 * 1024 + 255) / 256, 256, 0, stream>>>(we2, Wt2, 1024, 1024);
  wprep1<<<(256 * 1024 + 255) / 256, 256, 0, stream>>>(we3, Wt3, 200, 256, 1024);
  conv_mfma<9, 1, 1, 3><<<896, 256, 0, stream>>>(featp, Wt1, be1, h1p, 512, 1024, 1024);
  conv_mfma<9, 1, 1, 3><<<896, 256, 0, stream>>>(h1p, Wt2, be2, h2p, 1024, 1024, 1024);
  conv_mfma<1, 0, 0, 1><<<224, 256, 0, stream>>>(h2p, Wt3, be3, outbuf, 1024, 256, 200);
  logits_atten<0><<<32, 256, 0, stream>>>(outbuf, nullptr, outv + 6400, nullptr);
}

// Round 9
// 3285.162 us; speedup vs baseline: 1.0664x; 1.0664x over previous
//
#include <hip/hip_runtime.h>
#include <hip/hip_bf16.h>
#include <stdint.h>

// ---------------------------------------------------------------------------
// VGG attention-erase pipeline, bf16 MFMA implicit-im2col convs.
// Activations channels-last, spatially padded: [b][30 rows][32 cols][C] bf16.
// Weights pre-transposed to [p=9][O][C] bf16.
// conv_mfma v8 == v6 schedule (best: 974us/conv) with ONE change:
//   stageA aux 2 -> 0. The NT flag was bypassing L3 as well as L2, sending
//   the whole 0.67GB act stream to HBM at multi-us queued latency (v6 FETCH
//   decomposition: 1.01GB ~= 0.15GB W-compulsory + ~0.67GB A-issued).
//   With aux=0, A first-touch hits L3 (h1p/featp are L3-resident, ~600cyc),
//   and the per-XCD W panel stays L2-hot (re-touched every phase by 64
//   blocks; A-stream pressure ~165KB per reuse interval << 4MB L2).
//  - weights: 4 x 8KB LDS ring, lead-3, counted vmcnt FIFO (v5/v6).
//  - two barriers per phase (overwrite-safety / arrival).
//  - panel-per-XCD grid (panel = id & (2^XBITS-1)).
//  - coalesced LDS-staged epilogue (full 128B store segments).
//  LDS 80KB/block = 2 blocks/CU; 128 VGPR + 112 acc = 2 waves/SIMD.
// ---------------------------------------------------------------------------

typedef __attribute__((ext_vector_type(8))) short short8;
typedef __attribute__((ext_vector_type(4))) float floatx4;

__device__ __forceinline__ unsigned short f2bf(float f) {
  union { float f; uint32_t u; } cv; cv.f = f;
  uint32_t u = cv.u;
  u += 0x7fffu + ((u >> 16) & 1u);   // round-to-nearest-even
  return (unsigned short)(u >> 16);
}

// ---------------- weight prep: w[O][C][3][3] f32 -> wt[9][O][C] bf16 --------
__global__ void wprep3(const float* __restrict__ w, unsigned short* __restrict__ wt,
                       int O, int C) {
  int i = blockIdx.x * 256 + threadIdx.x;
  int total = 9 * O * C;
  if (i >= total) return;
  int p = i / (O * C);
  int r = i - p * O * C;
  int o = r / C;
  int c = r - o * C;
  wt[i] = f2bf(w[(size_t)(o * C + c) * 9 + p]);
}

// -------------- weight prep 1x1: w[O][C] f32 -> wt[OP][C] bf16 (zero pad) ---
__global__ void wprep1(const float* __restrict__ w, unsigned short* __restrict__ wt,
                       int O, int OP, int C) {
  int i = blockIdx.x * 256 + threadIdx.x;
  if (i >= OP * C) return;
  int o = i / C, c = i - o * C;
  wt[i] = (o < O) ? f2bf(w[(size_t)o * C + c]) : (unsigned short)0;
}

// ------ avgpool 3x3/9 (count_include_pad) + transpose to ch-last padded -----
// x: [32][512][28][28] f32  ->  fp: [32][30][32][512] bf16 (borders zero)
__global__ void avgpool_k(const float* __restrict__ x, unsigned short* __restrict__ fp) {
  const int C = 512;
  int b = blockIdx.x, r = blockIdx.y, cg = blockIdx.z;  // r: padded row 0..29
  int t = threadIdx.x;
  __shared__ float xs[3 * 128 * 29];   // stride 29 to kill bank conflicts
  if (r == 0 || r == 29) {
    for (int i = t; i < 32 * 128; i += 256) {
      int c = i & 127, col = i >> 7;
      fp[((size_t)(b * 30 + r) * 32 + col) * C + cg * 128 + c] = 0;
    }
    return;
  }
  for (int i = t; i < 3 * 128 * 28; i += 256) {
    int dy = i / 3584;
    int rem = i - dy * 3584;
    int c = rem / 28, fx = rem - c * 28;
    int fy = r - 2 + dy;
    float v = (fy >= 0 && fy < 28)
                  ? x[((size_t)(b * 512 + cg * 128 + c) * 28 + fy) * 28 + fx]
                  : 0.f;
    xs[(dy * 128 + c) * 29 + fx] = v;
  }
  __syncthreads();
  for (int i = t; i < 32 * 128; i += 256) {
    int c = i & 127, col = i >> 7;
    float v = 0.f;
    if (col >= 1 && col <= 28) {
      int fx0 = col - 1;
#pragma unroll
      for (int dy = 0; dy < 3; ++dy)
#pragma unroll
        for (int dx = 0; dx < 3; ++dx) {
          int fx = fx0 - 1 + dx;
          if (fx >= 0 && fx < 28) v += xs[(dy * 128 + c) * 29 + fx];
        }
      v *= (1.f / 9.f);
    }
    fp[((size_t)(b * 30 + r) * 32 + col) * C + cg * 128 + c] = f2bf(v);
  }
}

// ---------- zero the padded borders of h1p/h2p (ws is poisoned per call) ----
__global__ void zero_borders(unsigned short* __restrict__ h1,
                             unsigned short* __restrict__ h2, int Mch) {
  int i = blockIdx.x * 256 + threadIdx.x;
  int vch = Mch >> 3;                      // uint4 = 8 bf16
  int perbuf = 32 * 176 * vch;
  if (i >= 2 * perbuf) return;
  unsigned short* h = (i < perbuf) ? h1 : h2;
  int j = (i < perbuf) ? i : i - perbuf;
  int cv = j % vch;
  int rr = j / vch;
  int bidx = rr / 176, e = rr - bidx * 176;
  int row, col;
  if (e < 32)      { row = 0;  col = e; }
  else if (e < 64) { row = 29; col = e - 32; }
  else {
    int q = e - 64;
    row = 1 + (q >> 2);
    int k = q & 3;
    col = (k == 0) ? 0 : 28 + k;           // cols 0,29,30,31
  }
  size_t addr = ((size_t)(bidx * 30 + row) * 32 + col) * Mch + cv * 8;
  *(uint4*)&h[addr] = (uint4){0u, 0u, 0u, 0u};
}

// ------------------------------- the conv GEMM ------------------------------
// fin: [B][30][32][C] bf16, wt: [P][M][C] bf16, bias: [OB] f32
// PADOUT=1: out bf16 [B][30][32][M] (interior only). PADOUT=0: out f32 [B][784][M].
// grid 1D: panel = id & (2^XBITS-1) (panel-per-XCD); s = id >> XBITS.
template <int P, int RELU, int PADOUT, int XBITS>
__global__ __launch_bounds__(256, 2)
void conv_mfma(const unsigned short* __restrict__ fin,
               const unsigned short* __restrict__ wt,
               const float* __restrict__ bias,
               void* __restrict__ outp, int C, int M, int OB) {
  const int tid = threadIdx.x;
  const int lane = tid & 63;
  const int wave = tid >> 6;
  const int hB = wave & 1;      // batch half
  const int wo = wave >> 1;     // outch half
  const int ln = lane & 15;
  const int kq = lane >> 4;

  const int id = blockIdx.x;
  const int xo = id & ((1 << XBITS) - 1);   // weight panel (== XCD residue)
  const int s  = id >> XBITS;               // spatial-batch tile 0..111
  const int yo = s % 7;
  const int bz = s / 7;

  const int o0 = xo * 128 + wo * 64;
  const int wO0 = xo * 128;                 // block weight-row base (128 wide)
  const int yo0 = yo * 4;                   // first output row of tile
  const int b0 = bz * 2;
  const int bb = b0 + hB;

  // one LDS pool: [A: 2 x 1536 units][W: 4 x 512 units]; epilogue reuses it.
  __shared__ unsigned short ldsAll[40960];        // 81920 B
  unsigned short* ldsA = ldsAll;                  // 24576 shorts (49152 B)
  unsigned short* ldsW = ldsAll + 24576;          // 16384 shorts (32768 B)

  // spatial decomposition for A-fragment reads (m = ln within each 16-tile)
  int baserc[7];
#pragma unroll
  for (int mi = 0; mi < 7; ++mi) {
    int n = mi * 16 + ln;
    int y = n / 28, x = n - y * 28;
    baserc[mi] = y * 32 + x;
  }
  // weight fragment LDS offset (shorts): row = wo*64 + ni*16 + ln, swz unit kq
  const int wbase = wo * 2048 + ln * 32 + ((kq ^ (ln & 3)) << 3);

  floatx4 acc[7][4];
#pragma unroll
  for (int mi = 0; mi < 7; ++mi)
#pragma unroll
    for (int ni = 0; ni < 4; ++ni)
      acc[mi][ni] = (floatx4){0.f, 0.f, 0.f, 0.f};

  const size_t fin_base0 = (size_t)(b0 * 30 + yo0) * 32 * C;
  const size_t fin_base1 = (size_t)((b0 + 1) * 30 + yo0) * 32 * C;

  // per-thread staging constants (XOR swizzle on 16B-unit index, same scheme
  // for act and wgt; invariant because chunk strides are multiples of 4)
  const int rA = tid >> 2;                  // row-within-256-unit chunk
  const int cgA = (tid & 3) ^ (rA & 3);     // swizzled 16B column group

  auto stageA = [&](int ck, int buf) {
#pragma unroll
    for (int it = 0; it < 6; ++it) {
      int wb = (it >= 3) ? 1 : 0;
      int it3 = it - wb * 3;
      int rc = it3 * 64 + rA;
      size_t goff = (wb ? fin_base1 : fin_base0) + (size_t)rc * C + ck + cgA * 8;
      unsigned short* lp = &ldsA[(unsigned)(buf * 1536 + wb * 768 + it3 * 256 + wave * 64) << 3];
      // aux=0: allocate normally -> A first-touch hits L3 (h1p/featp are
      // L3-resident); NT (aux=2) bypassed L3 and pushed 0.67GB to HBM.
      __builtin_amdgcn_global_load_lds((const uint32_t*)(fin + goff), (uint32_t*)lp,
                                       16, 0, 0);
    }
  };
  auto stageW = [&](int p, int ck, int q) {   // q: ring slot 0..3
#pragma unroll
    for (int it = 0; it < 2; ++it) {
      int row = it * 64 + rA;
      size_t goff = (size_t)(p * M + wO0 + row) * C + ck + cgA * 8;
      unsigned short* lp = &ldsW[(unsigned)(q * 512 + it * 256 + wave * 64) << 3];
      __builtin_amdgcn_global_load_lds((const uint32_t*)(wt + goff), (uint32_t*)lp,
                                       16, 0, 0);
    }
  };

  // prologue. FIFO (oldest->newest): A0(6), W0(2) [, W1(2), W2(2) for P==9]
  stageA(0, 0);
  stageW(0, 0, 0);
  if (P == 9) { stageW(1, 0, 1); stageW(2, 0, 2); }

  int cur = 0;    // act read buffer
  int rq0 = 0;    // W ring slot of this chunk's phase 0  (global phase t mod 4)
  for (int ck = 0; ck < C; ck += 32) {
    const bool last = (ck + 32 >= C);
#pragma unroll
    for (int p = 0; p < P; ++p) {
      const bool fin_phase = last && (p == P - 1);

      // ---- barrier1: every wave is done READING the ring slots / A buffer
      //      that the stages below overwrite.
      __builtin_amdgcn_s_barrier();
      __builtin_amdgcn_sched_barrier(0);

      // ---- issue stages (no destination VGPRs; vmcnt-tracked FIFO).
      if (P == 9) {
        if (!(last && p >= 6))
          stageW(p < 6 ? p + 3 : p - 6, p < 6 ? ck : ck + 32, (rq0 + p + 3) & 3);
      } else {
        if (!last) stageW(0, ck + 32, (rq0 + p + 1) & 3);
      }
      if (p == 0 && !last) stageA(ck + 32, cur ^ 1);

      // ---- counted wait (FIFO accounting identical to v5/v6; verified).
      if (P == 9) {
        if (fin_phase)           asm volatile("s_waitcnt vmcnt(0)" ::: "memory");
        else if (last && p == 6) asm volatile("s_waitcnt vmcnt(4)" ::: "memory");
        else if (last && p == 7) asm volatile("s_waitcnt vmcnt(2)" ::: "memory");
        else if (last)           asm volatile("s_waitcnt vmcnt(6)" ::: "memory");
        else if (p <= 3)         asm volatile("s_waitcnt vmcnt(12)" ::: "memory");
        else                     asm volatile("s_waitcnt vmcnt(6)" ::: "memory");
      } else {
        if (last)                asm volatile("s_waitcnt vmcnt(0)" ::: "memory");
        else                     asm volatile("s_waitcnt vmcnt(8)" ::: "memory");
      }
      __builtin_amdgcn_sched_barrier(0);

      // ---- barrier2: all waves' loads for this phase are complete.
      __builtin_amdgcn_s_barrier();
      __builtin_amdgcn_sched_barrier(0);
      asm volatile("" ::: "memory");   // no LDS read hoists above this point

      // ---- compute phase p from LDS ----
      const unsigned short* wrd = &ldsW[(unsigned)(((rq0 + p) & 3) << 12)];
      const unsigned short* ard = &ldsA[cur ? 12288 : 0];
      int dy, dx;
      if (P == 1) { dy = 1; dx = 1; } else { dy = p / 3; dx = p - dy * 3; }
      short8 wf[4];
#pragma unroll
      for (int ni = 0; ni < 4; ++ni)
        wf[ni] = *(const short8*)(const void*)&wrd[wbase + ni * 512];
      short8 af[7];
#pragma unroll
      for (int mi = 0; mi < 7; ++mi) {
        int rc = baserc[mi] + dy * 32 + dx;
        int u = hB * 768 + (rc << 2) + (kq ^ (rc & 3));
        af[mi] = *(const short8*)(const void*)&ard[(unsigned)u << 3];
      }
      __builtin_amdgcn_s_setprio(1);
#pragma unroll
      for (int mi = 0; mi < 7; ++mi)
#pragma unroll
        for (int ni = 0; ni < 4; ++ni)
          acc[mi][ni] = __builtin_amdgcn_mfma_f32_16x16x32_bf16(af[mi], wf[ni],
                                                                acc[mi][ni], 0, 0, 0);
      __builtin_amdgcn_s_setprio(0);
    }
    rq0 = (rq0 + P) & 3;
    cur ^= 1;
  }

  // ---- epilogue ----  D[row=spatial=(kq*4+j within 16-tile)][col=outch=ln]
  float bia[4];
#pragma unroll
  for (int ni = 0; ni < 4; ++ni) {
    int o = o0 + ni * 16 + ln;
    bia[ni] = (o < OB) ? bias[o] : 0.f;
  }

  if (PADOUT) {
    // coalesced path: stage wave tile (112 rows x 64 outch bf16) in LDS
    // (stride 72 shorts = 144B, 16B-aligned rows), then 14 x dwordx4/lane.
    __builtin_amdgcn_s_barrier();   // all waves done reading ldsA/ldsW
    unsigned short* ep = ldsAll + wave * 8064;   // 112*72 shorts per wave
#pragma unroll
    for (int mi = 0; mi < 7; ++mi)
#pragma unroll
      for (int j = 0; j < 4; ++j) {
        int n = mi * 16 + kq * 4 + j;
#pragma unroll
        for (int ni = 0; ni < 4; ++ni) {
          float v = acc[mi][ni][j] + bia[ni];
          if (RELU) v = fmaxf(v, 0.f);
          ep[n * 72 + ni * 16 + ln] = f2bf(v);
        }
      }
    // same-wave producer/consumer: lgkmcnt drain is enough (no cross-wave)
    asm volatile("s_waitcnt lgkmcnt(0)" ::: "memory");
    __builtin_amdgcn_sched_barrier(0);
    const int rsub = lane >> 3;          // row within 8-row group
    const int oseg = (lane & 7) * 8;     // 8 bf16 = 16B segment
#pragma unroll
    for (int it = 0; it < 14; ++it) {
      int n = it * 8 + rsub;
      int y = n / 28, x = n - y * 28;
      uint4 v = *(const uint4*)&ep[n * 72 + oseg];
      size_t addr = ((size_t)(bb * 30 + yo0 + y + 1) * 32 + (x + 1)) * M + o0 + oseg;
      *(uint4*)&((unsigned short*)outp)[addr] = v;
    }
  } else {
#pragma unroll
    for (int mi = 0; mi < 7; ++mi) {
#pragma unroll
      for (int j = 0; j < 4; ++j) {
        int n = mi * 16 + kq * 4 + j;
        int y = n / 28, x = n - y * 28;
#pragma unroll
        for (int ni = 0; ni < 4; ++ni) {
          int o = o0 + ni * 16 + ln;
          float v = acc[mi][ni][j] + bia[ni];
          if (RELU) v = fmaxf(v, 0.f);
          size_t addr = ((size_t)bb * 784 + (yo0 + y) * 28 + x) * M + o;
          ((float*)outp)[addr] = v;
        }
      }
    }
  }
}

// ------------- logits (+ optional attention/mask), one block per batch ------
// ob: [32][784][256] f32 (cols 200..255 are zero)
template <int DO_ATTEN>
__global__ void logits_atten(const float* __restrict__ ob, const int* __restrict__ label,
                             float* __restrict__ outp, float* __restrict__ mask) {
  int b = blockIdx.x, t = threadIdx.x;
  const float* base = ob + (size_t)b * 784 * 256;
  float s = 0.f;
#pragma unroll 16
  for (int n = 0; n < 784; ++n) s += base[(size_t)n * 256 + t];
  if (t < 200) outp[b * 200 + t] = 1.f / (1.f + expf(-s * (1.f / 784.f)));

  if (DO_ATTEN) {
    __shared__ float labf[256];
    __shared__ float red[16];
    labf[t] = (t < 200) ? (float)label[b * 200 + t] : 0.f;
    __syncthreads();
    // normalization is invariant to the /cnt scaling -> skip it
    float att[4];
    float mn = 1e30f, mx = -1e30f;
#pragma unroll
    for (int i = 0; i < 4; ++i) {
      int n = t + i * 256;
      float a = 0.f;
      if (n < 784) {
        const float* rowp = base + (size_t)n * 256;
#pragma unroll 8
        for (int c = 0; c < 200; ++c) a += labf[c] * rowp[c];
        mn = fminf(mn, a);
        mx = fmaxf(mx, a);
      }
      att[i] = a;
    }
    for (int off = 32; off; off >>= 1) {
      mn = fminf(mn, __shfl_down(mn, off, 64));
      mx = fmaxf(mx, __shfl_down(mx, off, 64));
    }
    if ((t & 63) == 0) { red[(t >> 6) * 2] = mn; red[(t >> 6) * 2 + 1] = mx; }
    __syncthreads();
    if (t == 0) {
      float a = red[0], c = red[1];
      for (int wv = 1; wv < 4; ++wv) {
        a = fminf(a, red[wv * 2]);
        c = fmaxf(c, red[wv * 2 + 1]);
      }
      red[0] = a; red[1] = c;
    }
    __syncthreads();
    float gmn = red[0];
    float inv = 1.f / (red[1] - gmn);
#pragma unroll
    for (int i = 0; i < 4; ++i) {
      int n = t + i * 256;
      if (n < 784)
        mask[b * 784 + n] = ((att[i] - gmn) * inv >= 0.6f) ? 0.f : 1.f;
    }
  }
}

// ------------------- erase: featp interior *= mask (in place) ---------------
__global__ void erase_k(unsigned short* __restrict__ fp, const float* __restrict__ mask) {
  int i = blockIdx.x * 256 + threadIdx.x;
  if (i >= 32 * 28 * 28 * 512) return;
  int c = i & 511;
  int r2 = i >> 9;
  int xcol = r2 % 28;
  int r3 = r2 / 28;
  int y = r3 % 28;
  int b = r3 / 28;
  if (mask[b * 784 + y * 28 + xcol] == 0.f)
    fp[((size_t)(b * 30 + y + 1) * 32 + (xcol + 1)) * 512 + c] = 0;
}

// ---------------------------------------------------------------------------
extern "C" void kernel_launch(void* const* d_in, const int* in_sizes, int n_in,
                              void* d_out, int out_size, void* d_ws, size_t ws_size,
                              hipStream_t stream) {
  const float* x   = (const float*)d_in[0];
  const int* label = (const int*)d_in[1];
  const float* w1  = (const float*)d_in[2];
  const float* b1  = (const float*)d_in[3];
  const float* w2  = (const float*)d_in[4];
  const float* b2  = (const float*)d_in[5];
  const float* w3  = (const float*)d_in[6];
  const float* b3  = (const float*)d_in[7];
  const float* we1 = (const float*)d_in[8];
  const float* be1 = (const float*)d_in[9];
  const float* we2 = (const float*)d_in[10];
  const float* be2 = (const float*)d_in[11];
  const float* we3 = (const float*)d_in[12];
  const float* be3 = (const float*)d_in[13];
  float* outv = (float*)d_out;

  char* wp = (char*)d_ws;
  unsigned short* featp = (unsigned short*)wp; wp += 31457280;   // [32][30][32][512] bf16
  unsigned short* h1p   = (unsigned short*)wp; wp += 62914560;   // [32][30][32][1024] bf16
  unsigned short* h2p   = (unsigned short*)wp; wp += 62914560;
  unsigned short* Wt1   = (unsigned short*)wp; wp += 9437184;    // [9][1024][512]
  unsigned short* Wt2   = (unsigned short*)wp; wp += 18874368;   // [9][1024][1024]
  unsigned short* Wt3   = (unsigned short*)wp; wp += 524288;     // [256][1024]
  float* outbuf         = (float*)wp;          wp += 25690112;   // [32][784][256] f32
  float* maskb          = (float*)wp;          wp += 100352;     // [32][784]

  // prep (every launch: ws is re-poisoned by the harness)
  zero_borders<<<5632, 256, 0, stream>>>(h1p, h2p, 1024);
  avgpool_k<<<dim3(32, 30, 4), 256, 0, stream>>>(x, featp);
  wprep3<<<(9 * 1024 * 512 + 255) / 256, 256, 0, stream>>>(w1, Wt1, 1024, 512);
  wprep3<<<(9 * 1024 * 1024 + 255) / 256, 256, 0, stream>>>(w2, Wt2, 1024, 1024);
  wprep1<<<(256 * 1024 + 255) / 256, 256, 0, stream>>>(w3, Wt3, 200, 256, 1024);

  // head 1 (1D grids, panel = id & (2^XBITS-1) -> panel-per-XCD)
  conv_mfma<9, 1, 1, 3><<<896, 256, 0, stream>>>(featp, Wt1, b1, h1p, 512, 1024, 1024);
  conv_mfma<9, 1, 1, 3><<<896, 256, 0, stream>>>(h1p, Wt2, b2, h2p, 1024, 1024, 1024);
  conv_mfma<1, 0, 0, 1><<<224, 256, 0, stream>>>(h2p, Wt3, b3, outbuf, 1024, 256, 200);
  logits_atten<1><<<32, 256, 0, stream>>>(outbuf, label, outv, maskb);

  // erase + head 2 (reuse Wt/h buffers; h borders are still zero)
  erase_k<<<(32 * 28 * 28 * 512 + 255) / 256, 256, 0, stream>>>(featp, maskb);
  wprep3<<<(9 * 1024 * 512 + 255) / 256, 256, 0, stream>>>(we1, Wt1, 1024, 512);
  wprep3<<<(9 * 1024 * 1024 + 255) / 256, 256, 0, stream>>>(we2, Wt2, 1024, 1024);
  wprep1<<<(256 * 1024 + 255) / 256, 256, 0, stream>>>(we3, Wt3, 200, 256, 1024);
  conv_mfma<9, 1, 1, 3><<<896, 256, 0, stream>>>(featp, Wt1, be1, h1p, 512, 1024, 1024);
  conv_mfma<9, 1, 1, 3><<<896, 256, 0, stream>>>(h1p, Wt2, be2, h2p, 1024, 1024, 1024);
  conv_mfma<1, 0, 0, 1><<<224, 256, 0, stream>>>(h2p, Wt3, be3, outbuf, 1024, 256, 200);
  logits_atten<0><<<32, 256, 0, stream>>>(outbuf, nullptr, outv + 6400, nullptr);
}